// Round 1
// baseline (1247.995 us; speedup 1.0000x reference)
//
#include <hip/hip_runtime.h>
#include <math.h>

#define BSZ   64
#define TLEN  512
#define ODIM  50000
#define HDIM  2048
#define K1DIM 2560
#define K2DIM 4096
#define KSPLIT 5

typedef __bf16 bf16x8 __attribute__((ext_vector_type(8)));
typedef float f32x4 __attribute__((ext_vector_type(4)));

__device__ __forceinline__ unsigned short f2b(float f) {
    unsigned int u = __float_as_uint(f);
    u += 0x7FFFu + ((u >> 16) & 1u);
    return (unsigned short)(u >> 16);
}

__device__ __forceinline__ bf16x8 ld_bf16x8(const unsigned short* p) {
    union { uint4 u; bf16x8 v; } x;
    x.u = *reinterpret_cast<const uint4*>(p);
    return x.v;
}

// ---------------- K0: build bf16 A matrices ----------------
// ctx (64 x 2560) from E_table gather; enc into A2 columns [2048,4096)
__global__ __launch_bounds__(256) void prep_kernel(
    const float* __restrict__ enc, const int* __restrict__ ps,
    const float* __restrict__ Et, unsigned short* __restrict__ ctx,
    unsigned short* __restrict__ A2)
{
    int i = blockIdx.x * 256 + threadIdx.x;
    const int NE = BSZ * HDIM;
    if (i < NE) {
        int m = i >> 11, j = i & (HDIM - 1);
        A2[m * K2DIM + HDIM + j] = f2b(enc[i]);
    } else {
        int t = i - NE;  // 0 .. 64*2560-1 (grid sized exactly)
        int m = t / K1DIM, j = t - m * K1DIM;
        int c = j >> 9, e = j & 511;
        int tok = ps[m * 8 + 3 + c];
        ctx[m * K1DIM + j] = f2b(Et[(size_t)tok * 512 + e]);
    }
}

// ---------------- K1: GEMM1 partials: ctx @ W1 ----------------
// grid (32, 5): 64-wide n tile, K split in 5 chunks of 512
__global__ __launch_bounds__(256) void gemm1_kernel(
    const unsigned short* __restrict__ Actx, const float* __restrict__ W1,
    float* __restrict__ part)
{
    int n0 = blockIdx.x * 64;
    int ks = blockIdx.y;
    int wave = threadIdx.x >> 6;
    int lane = threadIdx.x & 63;
    int q = lane >> 4, l16 = lane & 15;
    int ncol = n0 + wave * 16 + l16;

    f32x4 acc[4] = {};
    for (int kk = 0; kk < 16; ++kk) {
        int kq = ks * 512 + kk * 32 + q * 8;
        const unsigned short* ap = Actx + l16 * K1DIM + kq;
        bf16x8 a0 = ld_bf16x8(ap);
        bf16x8 a1 = ld_bf16x8(ap + 16 * K1DIM);
        bf16x8 a2 = ld_bf16x8(ap + 32 * K1DIM);
        bf16x8 a3 = ld_bf16x8(ap + 48 * K1DIM);
        const float* wp = W1 + (size_t)kq * HDIM + ncol;
        union { unsigned short s[8]; bf16x8 v; } bb;
#pragma unroll
        for (int j = 0; j < 8; ++j) { bb.s[j] = f2b(*wp); wp += HDIM; }
        acc[0] = __builtin_amdgcn_mfma_f32_16x16x32_bf16(a0, bb.v, acc[0], 0, 0, 0);
        acc[1] = __builtin_amdgcn_mfma_f32_16x16x32_bf16(a1, bb.v, acc[1], 0, 0, 0);
        acc[2] = __builtin_amdgcn_mfma_f32_16x16x32_bf16(a2, bb.v, acc[2], 0, 0, 0);
        acc[3] = __builtin_amdgcn_mfma_f32_16x16x32_bf16(a3, bb.v, acc[3], 0, 0, 0);
    }
    float* pp = part + (size_t)ks * (BSZ * HDIM);
#pragma unroll
    for (int mt = 0; mt < 4; ++mt)
#pragma unroll
        for (int r = 0; r < 4; ++r)
            pp[(mt * 16 + q * 4 + r) * HDIM + ncol] = acc[mt][r];
}

// ---------------- K1b: reduce partials + bias + tanh -> bf16 h into A2[:, :2048]
__global__ __launch_bounds__(256) void htanh_kernel(
    const float* __restrict__ part, const float* __restrict__ b1,
    unsigned short* __restrict__ A2)
{
    int i = blockIdx.x * 256 + threadIdx.x;  // 64*2048 exact
    int m = i >> 11, n = i & (HDIM - 1);
    float s = b1[n];
#pragma unroll
    for (int ks = 0; ks < KSPLIT; ++ks) s += part[(size_t)ks * (BSZ * HDIM) + m * HDIM + n];
    A2[m * K2DIM + n] = f2b(tanhf(s));
}

// ---------------- K2: big GEMM: [h,enc] @ [W2;W3] + b2 + b3 -> logits ----------------
// grid 784 blocks, 64-wide n tiles, XCD-swizzled so each XCD owns a contiguous band
__global__ __launch_bounds__(256) void gemm2_kernel(
    const unsigned short* __restrict__ A, const float* __restrict__ W2,
    const float* __restrict__ W3, const float* __restrict__ b2,
    const float* __restrict__ b3, float* __restrict__ out)
{
    int bid = blockIdx.x;
    int xcd = bid & 7;
    int slot = bid >> 3;
    int tile = xcd * 98 + slot;   // 784 = 98*8 tiles
    int n0 = tile * 64;
    if (n0 >= ODIM) return;
    int wave = threadIdx.x >> 6;
    int lane = threadIdx.x & 63;
    int q = lane >> 4, l16 = lane & 15;
    int ncol = n0 + wave * 16 + l16;
    int nc = ncol < ODIM ? ncol : (ODIM - 1);  // clamp loads on partial tile

    f32x4 acc[4] = {};
    for (int k0 = 0; k0 < K2DIM; k0 += 32) {
        int kq = k0 + q * 8;
        const unsigned short* ap = A + l16 * K2DIM + kq;
        bf16x8 a0 = ld_bf16x8(ap);
        bf16x8 a1 = ld_bf16x8(ap + 16 * K2DIM);
        bf16x8 a2 = ld_bf16x8(ap + 32 * K2DIM);
        bf16x8 a3 = ld_bf16x8(ap + 48 * K2DIM);
        const float* W = (k0 < HDIM) ? W2 : W3;
        int kr = (k0 < HDIM) ? kq : (kq - HDIM);
        const float* wp = W + (size_t)kr * ODIM + nc;
        union { unsigned short s[8]; bf16x8 v; } bb;
#pragma unroll
        for (int j = 0; j < 8; ++j) { bb.s[j] = f2b(*wp); wp += ODIM; }
        acc[0] = __builtin_amdgcn_mfma_f32_16x16x32_bf16(a0, bb.v, acc[0], 0, 0, 0);
        acc[1] = __builtin_amdgcn_mfma_f32_16x16x32_bf16(a1, bb.v, acc[1], 0, 0, 0);
        acc[2] = __builtin_amdgcn_mfma_f32_16x16x32_bf16(a2, bb.v, acc[2], 0, 0, 0);
        acc[3] = __builtin_amdgcn_mfma_f32_16x16x32_bf16(a3, bb.v, acc[3], 0, 0, 0);
    }
    if (ncol < ODIM) {
        float bias = b2[ncol] + b3[ncol];
#pragma unroll
        for (int mt = 0; mt < 4; ++mt)
#pragma unroll
            for (int r = 0; r < 4; ++r)
                out[(size_t)(mt * 16 + q * 4 + r) * ODIM + ncol] = acc[mt][r] + bias;
    }
}

// ---------------- K3: n-gram / reorder features, added in place ----------------
// one block per batch row; dedup to first-occurrence so no atomics needed
__global__ __launch_bounds__(256) void feats_kernel(
    const int* __restrict__ src_g, const int* __restrict__ lens,
    const int* __restrict__ ps, float* __restrict__ out)
{
    __shared__ int src[TLEN];
    int b = blockIdx.x;
    int tid = threadIdx.x;
    for (int t = tid; t < TLEN; t += 256) src[t] = src_g[b * TLEN + t];
    __syncthreads();
    int len = lens[b];
    int w1 = ps[b * 8 + 7];
    int w2a = ps[b * 8 + 6];

    for (int t = tid; t < TLEN; t += 256) {
        int v = src[t];
        bool first = true, big = false, tri = false;
        int kp = TLEN;
        for (int j = 0; j < TLEN; ++j) {   // uniform loop: LDS broadcast reads
            int sj = src[j];
            int sj1 = (j < TLEN - 1) ? src[j + 1] : -1;
            int sj2 = (j < TLEN - 2) ? src[j + 2] : -1;
            if (j < t && sj == v) first = false;
            if (sj == w1 && sj1 == v) big = true;                    // bigram (w1,v) anywhere
            if (sj == w2a && sj1 == w1 && sj2 == v) tri = true;      // trigram (w2a,w1,v)
            if (sj == w1 && j < kp) kp = j;                          // first occurrence of w1
        }
        if (t < len && first) {
            bool in_list = kp < TLEN;
            bool reo = in_list && (t < kp);   // jpos(v)==t for first occurrence
            float add = 0.5f * (1.0f + (big ? 1.0f : 0.0f) + (tri ? 1.0f : 0.0f) + (reo ? 1.0f : 0.0f));
            out[(size_t)b * ODIM + v] += add;
        }
    }
}

// ---------------- K4a: per-row online max/sum ----------------
__global__ __launch_bounds__(256) void rowstats_kernel(
    const float* __restrict__ out, float* __restrict__ stats)
{
    int b = blockIdx.x, tid = threadIdx.x;
    const float* row = out + (size_t)b * ODIM;
    float m = -INFINITY, s = 0.0f;
    for (int i = tid; i < ODIM; i += 256) {
        float x = row[i];
        if (x > m) { s = s * __expf(m - x) + 1.0f; m = x; }
        else s += __expf(x - m);
    }
    __shared__ float ms[256], ss[256];
    ms[tid] = m; ss[tid] = s;
    __syncthreads();
    for (int off = 128; off > 0; off >>= 1) {
        if (tid < off) {
            float m1 = ms[tid], s1 = ss[tid];
            float m2 = ms[tid + off], s2 = ss[tid + off];
            float M = fmaxf(m1, m2);
            ss[tid] = s1 * __expf(m1 - M) + s2 * __expf(m2 - M);
            ms[tid] = M;
        }
        __syncthreads();
    }
    if (tid == 0) { stats[b] = ms[0]; stats[64 + b] = ss[0]; }
}

// ---------------- K4b: in-place normalize ----------------
__global__ __launch_bounds__(256) void norm_kernel(
    float* __restrict__ out, const float* __restrict__ stats)
{
    int i = blockIdx.x * 256 + threadIdx.x;  // 64 * 12500 float4 groups, exact
    int row = i / 12500;
    int off = i - row * 12500;
    float m = stats[row];
    float inv = 1.0f / stats[64 + row];
    float4* p = reinterpret_cast<float4*>(out + (size_t)row * ODIM) + off;
    float4 x = *p;
    x.x = __expf(x.x - m) * inv;
    x.y = __expf(x.y - m) * inv;
    x.z = __expf(x.z - m) * inv;
    x.w = __expf(x.w - m) * inv;
    *p = x;
}

extern "C" void kernel_launch(void* const* d_in, const int* in_sizes, int n_in,
                              void* d_out, int out_size, void* d_ws, size_t ws_size,
                              hipStream_t stream) {
    const float* enc  = (const float*)d_in[0];
    const int*   ps   = (const int*)d_in[1];
    const int*   src  = (const int*)d_in[2];
    const int*   lens = (const int*)d_in[3];
    const float* Et   = (const float*)d_in[4];
    const float* W1   = (const float*)d_in[5];
    const float* b1   = (const float*)d_in[6];
    const float* W2   = (const float*)d_in[7];
    const float* b2   = (const float*)d_in[8];
    const float* W3   = (const float*)d_in[9];
    const float* b3   = (const float*)d_in[10];
    float* out = (float*)d_out;

    char* ws = (char*)d_ws;
    unsigned short* ctx = (unsigned short*)(ws);                 // 64*2560*2 = 320 KB
    unsigned short* A2  = (unsigned short*)(ws + 524288);        // 64*4096*2 = 512 KB
    float* part         = (float*)(ws + 1048576);                // 5*64*2048*4 = 2.5 MB
    float* stats        = (float*)(ws + 3801088);                // 128 floats

    prep_kernel<<<1152, 256, 0, stream>>>(enc, ps, Et, ctx, A2);
    gemm1_kernel<<<dim3(32, KSPLIT), 256, 0, stream>>>(ctx, W1, part);
    htanh_kernel<<<512, 256, 0, stream>>>(part, b1, A2);
    gemm2_kernel<<<784, 256, 0, stream>>>(A2, W2, W3, b2, b3, out);
    feats_kernel<<<64, 256, 0, stream>>>(src, lens, ps, out);
    rowstats_kernel<<<64, 256, 0, stream>>>(out, stats);
    norm_kernel<<<3125, 256, 0, stream>>>(out, stats);
}

// Round 2
// 1170.044 us; speedup vs baseline: 1.0666x; 1.0666x over previous
//
#include <hip/hip_runtime.h>
#include <math.h>

#define BSZ   64
#define TLEN  512
#define ODIM  50000
#define HDIM  2048
#define K1DIM 2560
#define K2DIM 4096
#define KSPLIT 5

typedef __bf16 bf16x8 __attribute__((ext_vector_type(8)));
typedef float f32x4 __attribute__((ext_vector_type(4)));

__device__ __forceinline__ unsigned short f2b(float f) {
    unsigned int u = __float_as_uint(f);
    u += 0x7FFFu + ((u >> 16) & 1u);
    return (unsigned short)(u >> 16);
}

__device__ __forceinline__ bf16x8 ld_bf16x8(const unsigned short* p) {
    union { uint4 u; bf16x8 v; } x;
    x.u = *reinterpret_cast<const uint4*>(p);
    return x.v;
}

// ---------------- K0: build bf16 A matrices ----------------
__global__ __launch_bounds__(256) void prep_kernel(
    const float* __restrict__ enc, const int* __restrict__ ps,
    const float* __restrict__ Et, unsigned short* __restrict__ ctx,
    unsigned short* __restrict__ A2)
{
    int i = blockIdx.x * 256 + threadIdx.x;
    const int NE = BSZ * HDIM;
    if (i < NE) {
        int m = i >> 11, j = i & (HDIM - 1);
        A2[m * K2DIM + HDIM + j] = f2b(enc[i]);
    } else {
        int t = i - NE;
        int m = t / K1DIM, j = t - m * K1DIM;
        int c = j >> 9, e = j & 511;
        int tok = ps[m * 8 + 3 + c];
        ctx[m * K1DIM + j] = f2b(Et[(size_t)tok * 512 + e]);
    }
}

// ---------------- K1: GEMM1 partials: ctx @ W1 ----------------
__global__ __launch_bounds__(256) void gemm1_kernel(
    const unsigned short* __restrict__ Actx, const float* __restrict__ W1,
    float* __restrict__ part)
{
    int n0 = blockIdx.x * 64;
    int ks = blockIdx.y;
    int wave = threadIdx.x >> 6;
    int lane = threadIdx.x & 63;
    int q = lane >> 4, l16 = lane & 15;
    int ncol = n0 + wave * 16 + l16;

    f32x4 acc[4] = {};
    for (int kk = 0; kk < 16; ++kk) {
        int kq = ks * 512 + kk * 32 + q * 8;
        const unsigned short* ap = Actx + l16 * K1DIM + kq;
        bf16x8 a0 = ld_bf16x8(ap);
        bf16x8 a1 = ld_bf16x8(ap + 16 * K1DIM);
        bf16x8 a2 = ld_bf16x8(ap + 32 * K1DIM);
        bf16x8 a3 = ld_bf16x8(ap + 48 * K1DIM);
        const float* wp = W1 + (size_t)kq * HDIM + ncol;
        union { unsigned short s[8]; bf16x8 v; } bb;
#pragma unroll
        for (int j = 0; j < 8; ++j) { bb.s[j] = f2b(*wp); wp += HDIM; }
        acc[0] = __builtin_amdgcn_mfma_f32_16x16x32_bf16(a0, bb.v, acc[0], 0, 0, 0);
        acc[1] = __builtin_amdgcn_mfma_f32_16x16x32_bf16(a1, bb.v, acc[1], 0, 0, 0);
        acc[2] = __builtin_amdgcn_mfma_f32_16x16x32_bf16(a2, bb.v, acc[2], 0, 0, 0);
        acc[3] = __builtin_amdgcn_mfma_f32_16x16x32_bf16(a3, bb.v, acc[3], 0, 0, 0);
    }
    float* pp = part + (size_t)ks * (BSZ * HDIM);
#pragma unroll
    for (int mt = 0; mt < 4; ++mt)
#pragma unroll
        for (int r = 0; r < 4; ++r)
            pp[(mt * 16 + q * 4 + r) * HDIM + ncol] = acc[mt][r];
}

// ---------------- K1b: reduce partials + bias + tanh ----------------
__global__ __launch_bounds__(256) void htanh_kernel(
    const float* __restrict__ part, const float* __restrict__ b1,
    unsigned short* __restrict__ A2)
{
    int i = blockIdx.x * 256 + threadIdx.x;
    int m = i >> 11, n = i & (HDIM - 1);
    float s = b1[n];
#pragma unroll
    for (int ks = 0; ks < KSPLIT; ++ks) s += part[(size_t)ks * (BSZ * HDIM) + m * HDIM + n];
    A2[m * K2DIM + n] = f2b(tanhf(s));
}

// ---------------- K2: big GEMM, LDS-staged W, double-buffered ----------------
// N-tile 64, K-tile 64, [k][n] bf16 LDS tile, stride 136 B (conflict-free b64 writes)
#define KT 64
#define SKB 136
#define BUFB (KT * SKB)   // 8704 B per buffer

__global__ __launch_bounds__(256) void gemm2_kernel(
    const unsigned short* __restrict__ A, const float* __restrict__ W2,
    const float* __restrict__ W3, const float* __restrict__ b2,
    const float* __restrict__ b3, float* __restrict__ out)
{
    __shared__ char lds[2 * BUFB];
    int bid = blockIdx.x;
    int tile = (bid & 7) * 98 + (bid >> 3);   // XCD-contiguous bands
    if (tile >= 782) return;
    int n0 = tile * 64;

    int tid = threadIdx.x;
    int wave = tid >> 6;
    int lane = tid & 63;
    int q = lane >> 4, l16 = lane & 15;
    int ncol = n0 + wave * 16 + l16;
    int nloc = wave * 16 + l16;

    // staging assignment: round r covers rows r*16 + (tid>>4), cols (tid&15)*4
    int rr = tid >> 4;          // 0..15
    int cg = tid & 15;          // col group
    int gcol = n0 + cg * 4;
    if (gcol > ODIM - 4) gcol = ODIM - 4;   // clamp for partial tile 781

    float4 stage[4];
    // preload tile 0
#pragma unroll
    for (int r = 0; r < 4; ++r) {
        int krow = r * 16 + rr;           // 0..63, tile kt=0 => global row krow (< 2048: W2)
        stage[r] = *reinterpret_cast<const float4*>(W2 + (size_t)krow * ODIM + gcol);
    }

    f32x4 acc[4] = {};
    const unsigned short* abase = A + l16 * K2DIM;

    for (int kt = 0; kt < 64; ++kt) {
        char* buf = lds + (kt & 1) * BUFB;
        // convert + write staged tile to LDS
#pragma unroll
        for (int r = 0; r < 4; ++r) {
            union { unsigned short s[4]; unsigned long long u; } pk;
            pk.s[0] = f2b(stage[r].x);
            pk.s[1] = f2b(stage[r].y);
            pk.s[2] = f2b(stage[r].z);
            pk.s[3] = f2b(stage[r].w);
            *reinterpret_cast<unsigned long long*>(buf + (r * 16 + rr) * SKB + cg * 8) = pk.u;
        }
        __syncthreads();
        // issue next tile's global loads
        if (kt + 1 < 64) {
            int kg0 = (kt + 1) * KT;
#pragma unroll
            for (int r = 0; r < 4; ++r) {
                int krow = kg0 + r * 16 + rr;
                const float* src = (krow < HDIM) ? (W2 + (size_t)krow * ODIM)
                                                 : (W3 + (size_t)(krow - HDIM) * ODIM);
                stage[r] = *reinterpret_cast<const float4*>(src + gcol);
            }
        }
        // compute: two k32 halves from current buffer
#pragma unroll
        for (int h = 0; h < 2; ++h) {
            int kq = kt * KT + h * 32 + q * 8;
            const unsigned short* ap = abase + kq;
            bf16x8 a0 = ld_bf16x8(ap);
            bf16x8 a1 = ld_bf16x8(ap + 16 * K2DIM);
            bf16x8 a2 = ld_bf16x8(ap + 32 * K2DIM);
            bf16x8 a3 = ld_bf16x8(ap + 48 * K2DIM);
            union { unsigned short s[8]; bf16x8 v; } bb;
            const char* bp = buf + (h * 32 + q * 8) * SKB + nloc * 2;
#pragma unroll
            for (int j = 0; j < 8; ++j)
                bb.s[j] = *reinterpret_cast<const unsigned short*>(bp + j * SKB);
            acc[0] = __builtin_amdgcn_mfma_f32_16x16x32_bf16(a0, bb.v, acc[0], 0, 0, 0);
            acc[1] = __builtin_amdgcn_mfma_f32_16x16x32_bf16(a1, bb.v, acc[1], 0, 0, 0);
            acc[2] = __builtin_amdgcn_mfma_f32_16x16x32_bf16(a2, bb.v, acc[2], 0, 0, 0);
            acc[3] = __builtin_amdgcn_mfma_f32_16x16x32_bf16(a3, bb.v, acc[3], 0, 0, 0);
        }
    }

    if (ncol < ODIM) {
        float bias = b2[ncol] + b3[ncol];
#pragma unroll
        for (int mt = 0; mt < 4; ++mt)
#pragma unroll
            for (int r = 0; r < 4; ++r)
                out[(size_t)(mt * 16 + q * 4 + r) * ODIM + ncol] = acc[mt][r] + bias;
    }
}

// ---------------- K3: n-gram / reorder features ----------------
__global__ __launch_bounds__(256) void feats_kernel(
    const int* __restrict__ src_g, const int* __restrict__ lens,
    const int* __restrict__ ps, float* __restrict__ out)
{
    __shared__ int src[TLEN];
    int b = blockIdx.x;
    int tid = threadIdx.x;
    for (int t = tid; t < TLEN; t += 256) src[t] = src_g[b * TLEN + t];
    __syncthreads();
    int len = lens[b];
    int w1 = ps[b * 8 + 7];
    int w2a = ps[b * 8 + 6];

    for (int t = tid; t < TLEN; t += 256) {
        int v = src[t];
        bool first = true, big = false, tri = false;
        int kp = TLEN;
        for (int j = 0; j < TLEN; ++j) {
            int sj = src[j];
            int sj1 = (j < TLEN - 1) ? src[j + 1] : -1;
            int sj2 = (j < TLEN - 2) ? src[j + 2] : -1;
            if (j < t && sj == v) first = false;
            if (sj == w1 && sj1 == v) big = true;
            if (sj == w2a && sj1 == w1 && sj2 == v) tri = true;
            if (sj == w1 && j < kp) kp = j;
        }
        if (t < len && first) {
            bool in_list = kp < TLEN;
            bool reo = in_list && (t < kp);
            float add = 0.5f * (1.0f + (big ? 1.0f : 0.0f) + (tri ? 1.0f : 0.0f) + (reo ? 1.0f : 0.0f));
            out[(size_t)b * ODIM + v] += add;
        }
    }
}

// ---------------- K4a: per-row online max/sum ----------------
__global__ __launch_bounds__(256) void rowstats_kernel(
    const float* __restrict__ out, float* __restrict__ stats)
{
    int b = blockIdx.x, tid = threadIdx.x;
    const float* row = out + (size_t)b * ODIM;
    float m = -INFINITY, s = 0.0f;
    for (int i = tid; i < ODIM; i += 256) {
        float x = row[i];
        if (x > m) { s = s * __expf(m - x) + 1.0f; m = x; }
        else s += __expf(x - m);
    }
    __shared__ float ms[256], ss[256];
    ms[tid] = m; ss[tid] = s;
    __syncthreads();
    for (int off = 128; off > 0; off >>= 1) {
        if (tid < off) {
            float m1 = ms[tid], s1 = ss[tid];
            float m2 = ms[tid + off], s2 = ss[tid + off];
            float M = fmaxf(m1, m2);
            ss[tid] = s1 * __expf(m1 - M) + s2 * __expf(m2 - M);
            ms[tid] = M;
        }
        __syncthreads();
    }
    if (tid == 0) { stats[b] = ms[0]; stats[64 + b] = ss[0]; }
}

// ---------------- K4b: in-place normalize ----------------
__global__ __launch_bounds__(256) void norm_kernel(
    float* __restrict__ out, const float* __restrict__ stats)
{
    int i = blockIdx.x * 256 + threadIdx.x;
    int row = i / 12500;
    int off = i - row * 12500;
    float m = stats[row];
    float inv = 1.0f / stats[64 + row];
    float4* p = reinterpret_cast<float4*>(out + (size_t)row * ODIM) + off;
    float4 x = *p;
    x.x = __expf(x.x - m) * inv;
    x.y = __expf(x.y - m) * inv;
    x.z = __expf(x.z - m) * inv;
    x.w = __expf(x.w - m) * inv;
    *p = x;
}

extern "C" void kernel_launch(void* const* d_in, const int* in_sizes, int n_in,
                              void* d_out, int out_size, void* d_ws, size_t ws_size,
                              hipStream_t stream) {
    const float* enc  = (const float*)d_in[0];
    const int*   ps   = (const int*)d_in[1];
    const int*   src  = (const int*)d_in[2];
    const int*   lens = (const int*)d_in[3];
    const float* Et   = (const float*)d_in[4];
    const float* W1   = (const float*)d_in[5];
    const float* b1   = (const float*)d_in[6];
    const float* W2   = (const float*)d_in[7];
    const float* b2   = (const float*)d_in[8];
    const float* W3   = (const float*)d_in[9];
    const float* b3   = (const float*)d_in[10];
    float* out = (float*)d_out;

    char* ws = (char*)d_ws;
    unsigned short* ctx = (unsigned short*)(ws);
    unsigned short* A2  = (unsigned short*)(ws + 524288);
    float* part         = (float*)(ws + 1048576);
    float* stats        = (float*)(ws + 3801088);

    prep_kernel<<<1152, 256, 0, stream>>>(enc, ps, Et, ctx, A2);
    gemm1_kernel<<<dim3(32, KSPLIT), 256, 0, stream>>>(ctx, W1, part);
    htanh_kernel<<<512, 256, 0, stream>>>(part, b1, A2);
    gemm2_kernel<<<784, 256, 0, stream>>>(A2, W2, W3, b2, b3, out);
    feats_kernel<<<64, 256, 0, stream>>>(src, lens, ps, out);
    rowstats_kernel<<<64, 256, 0, stream>>>(out, stats);
    norm_kernel<<<3125, 256, 0, stream>>>(out, stats);
}